// Round 8
// baseline (1278.781 us; speedup 1.0000x reference)
//
#include <hip/hip_runtime.h>
#include <hip/hip_cooperative_groups.h>

namespace cg = cooperative_groups;

#define NN 50000      // nodes (fits in 16 bits: col packed as ushort)
#define NE 800000     // edges
#define DF 64         // features
#define MM 11         // (a,b) tuples
#define OUT_K 4       // DEPTH+1 output planes
#define PAD 8         // row slabs padded to multiple of PAD
// pair-max padding: each row pair padded to 2*max -> bounded by 2*sum
#define SLAB_CAP (2 * (NE + (PAD - 1) * NN) + 128)
#define GRID_CO 2048  // cooperative grid: 8 blocks/CU x 256 CU, exactly co-resident

typedef unsigned int uivec4 __attribute__((ext_vector_type(4)));

__device__ __forceinline__ float bf2f(unsigned short u) {
    union { unsigned int i; float f; } v; v.i = ((unsigned int)u) << 16; return v.f;
}
__device__ __forceinline__ unsigned short f2bf(float f) {
    union { float f; unsigned int i; } v; v.f = f;
    unsigned int u = v.i + 0x7FFFu + ((v.i >> 16) & 1u);
    return (unsigned short)(u >> 16);
}

// gamma[k][j] = sum_m w_m c_{k,m,j}: one m per lane, shuffle-reduce (wave 0 only).
__device__ __forceinline__ void gamma_calc(
        const float* __restrict__ alphas, const float* __restrict__ w,
        const float* __restrict__ a_arr, const float* __restrict__ b_arr,
        float* __restrict__ gamma, int lane) {
    float g[OUT_K][OUT_K];
    #pragma unroll
    for (int k = 0; k < OUT_K; ++k)
        #pragma unroll
        for (int j = 0; j < OUT_K; ++j) g[k][j] = 0.f;
    if (lane < MM) {
        int m = lane;
        float a = a_arr[m], b = b_arr[m], wm = w[m];
        float c[OUT_K][OUT_K];
        #pragma unroll
        for (int k = 0; k < OUT_K; ++k)
            #pragma unroll
            for (int j = 0; j < OUT_K; ++j) c[k][j] = 0.f;
        c[0][0] = 1.f;
        float al0 = alphas[m];
        c[1][0] = al0 * 0.5f * (a - b);        // l=-1, r=1
        c[1][1] = al0 * 0.5f * (a + b + 2.f);
        #pragma unroll
        for (int L = 2; L <= 3; ++L) {
            float Lf = (float)L;
            float alL = alphas[(L - 1) * MM + m];
            float alm = alphas[(L - 2) * MM + m];
            float ab = a + b;
            float t2L = 2.f * Lf + ab;
            float coef_l = 2.f * Lf * (Lf + ab) * (t2L - 2.f);
            float inv = 1.f / coef_l;
            float t1 = alL * ((t2L - 1.f) * t2L * (t2L - 2.f)) * inv;
            float t2 = alL * ((t2L - 1.f) * (a * a - b * b)) * inv;
            float t3 = alL * alm * (2.f * (Lf - 1.f + a) * (Lf - 1.f + b) * t2L) * inv;
            #pragma unroll
            for (int j = 0; j < OUT_K; ++j) {
                float ps = (j > 0) ? c[L - 1][j - 1] : 0.f;
                c[L][j] = t1 * ps - t2 * c[L - 1][j] - t3 * c[L - 2][j];
            }
        }
        #pragma unroll
        for (int k = 0; k < OUT_K; ++k)
            #pragma unroll
            for (int j = 0; j < OUT_K; ++j) g[k][j] = wm * c[k][j];
    }
    #pragma unroll
    for (int k = 0; k < OUT_K; ++k)
        #pragma unroll
        for (int j = 0; j < OUT_K; ++j) {
            float s = g[k][j];
            #pragma unroll
            for (int off = 32; off >= 1; off >>= 1) s += __shfl_down(s, off, 64);
            if (lane == 0) gamma[k * OUT_K + j] = s;
        }
}

// ------ SpMM core: wave = row PAIR; lanes 0-31 row 2w, lanes 32-63 row 2w+1 ------
// Each lane covers 2 features (one uint gather = 2 bf16). Table is dinv-prescaled.
__device__ __forceinline__ void spmm_pair(const unsigned int* __restrict__ ecv,
                                          int s, int m,
                                          const unsigned short* __restrict__ xin,
                                          int fp, float& a0, float& a1) {
    for (int i = 0; i < m; i += PAD) {
        const uivec4* p = (const uivec4*)(ecv + s + i);
        uivec4 q0 = __builtin_nontemporal_load(p);
        uivec4 q1 = __builtin_nontemporal_load(p + 1);
        unsigned int rec[PAD] = {q0.x, q0.y, q0.z, q0.w, q1.x, q1.y, q1.z, q1.w};
        unsigned int g[PAD];
        #pragma unroll
        for (int j = 0; j < PAD; ++j)
            g[j] = *(const unsigned int*)(xin + (rec[j] & 0xFFFFu) * DF + 2 * fp);
        #pragma unroll
        for (int j = 0; j < PAD; ++j) {
            float wf = __uint_as_float(rec[j] & 0xFFFF0000u);  // bf16 weight (ea)
            a0 = fmaf(wf, __uint_as_float(g[j] << 16), a0);
            a1 = fmaf(wf, __uint_as_float(g[j] & 0xFFFF0000u), a1);
        }
    }
}

// One SpMM layer over all pairs, grid-strided by wave; stores next prescaled table.
__device__ __forceinline__ void spmm_layer(
        const int* __restrict__ rowstart, const float* __restrict__ dinv,
        const unsigned int* __restrict__ ecv, const unsigned short* __restrict__ xin,
        unsigned short* __restrict__ bout, int wv0, int nw, int lane) {
    int h = lane >> 5, fp = lane & 31;
    for (int pv = wv0; pv < NN / 2; pv += nw) {
        int r = 2 * pv + h;
        int s = rowstart[r];
        int so = __shfl_xor(s, 32, 64);
        int m = h ? (s - so) : (so - s);     // common pair length
        float a0 = 0.f, a1 = 0.f;
        spmm_pair(ecv, s, m, xin, fp, a0, a1);
        float dv = dinv[r];
        float dv2 = dv * dv;
        a0 *= dv2; a1 *= dv2;
        unsigned int o = (unsigned int)f2bf(a0) | ((unsigned int)f2bf(a1) << 16);
        *(unsigned int*)(bout + r * DF + 2 * fp) = o;
    }
}

// ---------------- cooperative mega-kernel: all 6 phases, 5 grid syncs ----------------
__global__ __launch_bounds__(256, 8) void k_mega(
        const int* __restrict__ row, const int* __restrict__ col,
        const float* __restrict__ ea, const float* __restrict__ x,
        const float* __restrict__ alphas, const float* __restrict__ w,
        const float* __restrict__ a_arr, const float* __restrict__ b_arr,
        int* __restrict__ deg, int* __restrict__ counter,
        unsigned int* __restrict__ ecv, int* __restrict__ rowstart,
        float* __restrict__ dinv, float* __restrict__ sqd,
        unsigned short* __restrict__ rank,
        unsigned short* __restrict__ xb0, unsigned short* __restrict__ xb1,
        unsigned short* __restrict__ xb2,
        float* __restrict__ gamma, float* __restrict__ out) {
    cg::grid_group grid = cg::this_grid();
    const int tid  = blockIdx.x * blockDim.x + threadIdx.x;
    const int nthr = gridDim.x * blockDim.x;
    const int lane = threadIdx.x & 63;
    const int wv0  = tid >> 6;
    const int nw   = nthr >> 6;

    // ---- phase 1: degree + per-edge rank (atomic old value = slab slot) ----
    for (int e = tid; e < NE; e += nthr)
        rank[e] = (unsigned short)atomicAdd(&deg[row[e]], 1);
    grid.sync();

    // ---- phase 2: pair-max slab scan (one atomic/block) + dinv/sqd; gamma on spare block ----
    const int NB_SCAN = (NN + 255) / 256;
    if (blockIdx.x < NB_SCAN) {
        __shared__ int wtot[4];
        __shared__ int blockbase;
        int i = blockIdx.x * 256 + threadIdx.x;
        int wave = threadIdx.x >> 6;
        int d = (i < NN) ? deg[i] : 0;
        int dp = (d + PAD - 1) & ~(PAD - 1);
        int dpo = __shfl_xor(dp, 1, 64);      // pair partner's padded length
        int mp = max(dp, dpo);                // common pair length
        int v = mp;
        #pragma unroll
        for (int off = 1; off < 64; off <<= 1) {
            int t = __shfl_up(v, off, 64);
            if (lane >= off) v += t;
        }
        if (lane == 63) wtot[wave] = v;
        __syncthreads();
        if (wave == 0) {
            int t = (lane < 4) ? wtot[lane] : 0;
            int u = __shfl_up(t, 1, 64); if (lane >= 1) t += u;
            u = __shfl_up(t, 2, 64);     if (lane >= 2) t += u;
            if (lane == 3) blockbase = atomicAdd(counter, t);  // block total
            if (lane < 4) wtot[lane] = t;                      // inclusive scan
        }
        __syncthreads();
        int base = blockbase + (wave ? wtot[wave - 1] : 0);
        if (i < NN) {
            rowstart[i] = base + v - mp;      // even row: pair base; odd: base+m
            float dc = (float)(d == 0 ? 1 : d);
            float s = sqrtf(dc);
            sqd[i] = s;
            dinv[i] = 1.0f / s;
        }
    } else if (blockIdx.x == NB_SCAN && (threadIdx.x >> 6) == 0) {
        gamma_calc(alphas, w, a_arr, b_arr, gamma, lane);
    }
    grid.sync();

    // ---- phase 3: fill records (atomic-free) + prescaled bf16 cast of x ----
    for (int e = tid; e < NE; e += nthr) {
        int r = row[e], c = col[e];
        int pos = rowstart[r] + (int)rank[e];
        ecv[pos] = (unsigned int)(unsigned short)c | ((unsigned int)f2bf(ea[e]) << 16);
    }
    {
        const float4* xf = (const float4*)x;
        uint4* xo = (uint4*)xb0;
        for (int j = tid; j < (NN * DF) / 8; j += nthr) {
            float dv = dinv[j >> 3];               // 8 threads share a node
            float4 f0 = xf[2 * j];
            float4 f1 = xf[2 * j + 1];
            uint4 o;
            o.x = (unsigned int)f2bf(dv * f0.x) | ((unsigned int)f2bf(dv * f0.y) << 16);
            o.y = (unsigned int)f2bf(dv * f0.z) | ((unsigned int)f2bf(dv * f0.w) << 16);
            o.z = (unsigned int)f2bf(dv * f1.x) | ((unsigned int)f2bf(dv * f1.y) << 16);
            o.w = (unsigned int)f2bf(dv * f1.z) | ((unsigned int)f2bf(dv * f1.w) << 16);
            xo[j] = o;
        }
    }
    grid.sync();

    // ---- phases 4-5: two SpMM layers ----
    spmm_layer(rowstart, dinv, ecv, xb0, xb1, wv0, nw, lane);
    grid.sync();
    spmm_layer(rowstart, dinv, ecv, xb1, xb2, wv0, nw, lane);
    grid.sync();

    // ---- phase 6: third SpMM + output combine (y3 never hits memory) ----
    {
        int h = lane >> 5, fp = lane & 31;
        float gm[OUT_K * OUT_K];
        #pragma unroll
        for (int t = 0; t < OUT_K * OUT_K; ++t) gm[t] = gamma[t];
        for (int pv = wv0; pv < NN / 2; pv += nw) {
            int r = 2 * pv + h;
            int s = rowstart[r];
            int so = __shfl_xor(s, 32, 64);
            int m = h ? (s - so) : (so - s);
            float a0 = 0.f, a1 = 0.f;
            spmm_pair(ecv, s, m, xb2, fp, a0, a1);
            float dv = dinv[r];
            a0 *= dv; a1 *= dv;                   // v3 pair (y3 = dinv*raw)
            float sq = sqd[r];
            int base = r * DF + 2 * fp;
            float2 v0 = *(const float2*)(x + base);
            unsigned int u1 = *(const unsigned int*)(xb1 + base);
            unsigned int u2 = *(const unsigned int*)(xb2 + base);
            float v1l = __uint_as_float(u1 << 16) * sq;
            float v1h = __uint_as_float(u1 & 0xFFFF0000u) * sq;
            float v2l = __uint_as_float(u2 << 16) * sq;
            float v2h = __uint_as_float(u2 & 0xFFFF0000u) * sq;
            #pragma unroll
            for (int k = 0; k < OUT_K; ++k) {
                float2 o;
                o.x = gm[k * OUT_K + 0] * v0.x + gm[k * OUT_K + 1] * v1l +
                      gm[k * OUT_K + 2] * v2l + gm[k * OUT_K + 3] * a0;
                o.y = gm[k * OUT_K + 0] * v0.y + gm[k * OUT_K + 1] * v1h +
                      gm[k * OUT_K + 2] * v2h + gm[k * OUT_K + 3] * a1;
                *(float2*)(out + (r * OUT_K + k) * DF + 2 * fp) = o;
            }
        }
    }
}

// ---------------- fallback path (6 separate kernels, proven in R7) ----------------

__global__ void k_deg(const int* __restrict__ row, int* __restrict__ deg,
                      unsigned short* __restrict__ rank) {
    int e = blockIdx.x * blockDim.x + threadIdx.x;
    if (e < NE) {
        int r = row[e];
        rank[e] = (unsigned short)atomicAdd(&deg[r], 1);
    }
}

__global__ __launch_bounds__(1024) void k_alloc(
        const int* __restrict__ deg, int* __restrict__ counter,
        int* __restrict__ rowstart, float* __restrict__ dinv,
        float* __restrict__ sqd,
        const float* __restrict__ alphas, const float* __restrict__ w,
        const float* __restrict__ a_arr, const float* __restrict__ b_arr,
        float* __restrict__ gamma) {
    __shared__ int wtot[16];
    __shared__ int blockbase;
    int i = blockIdx.x * 1024 + threadIdx.x;
    int wave = threadIdx.x >> 6;
    int lane = threadIdx.x & 63;
    int d = (i < NN) ? deg[i] : 0;
    int dp = (d + PAD - 1) & ~(PAD - 1);
    int dpo = __shfl_xor(dp, 1, 64);
    int mp = max(dp, dpo);
    int v = mp;
    #pragma unroll
    for (int off = 1; off < 64; off <<= 1) {
        int t = __shfl_up(v, off, 64);
        if (lane >= off) v += t;
    }
    if (lane == 63) wtot[wave] = v;
    __syncthreads();
    if (wave == 0) {
        int t = (lane < 16) ? wtot[lane] : 0;
        #pragma unroll
        for (int off = 1; off < 16; off <<= 1) {
            int u = __shfl_up(t, off, 64);
            if (lane >= off) t += u;
        }
        if (lane == 15) blockbase = atomicAdd(counter, t);
        if (lane < 16) wtot[lane] = t;
    }
    __syncthreads();
    int base = blockbase + (wave ? wtot[wave - 1] : 0);
    if (i < NN) {
        rowstart[i] = base + v - mp;
        float dc = (float)(d == 0 ? 1 : d);
        float s = sqrtf(dc);
        sqd[i] = s;
        dinv[i] = 1.0f / s;
    }
    if (blockIdx.x == 0 && wave == 0)
        gamma_calc(alphas, w, a_arr, b_arr, gamma, lane);
}

__global__ void k_fill_cast(const int* __restrict__ row, const int* __restrict__ col,
                            const float* __restrict__ ea, const float* __restrict__ dinv,
                            const int* __restrict__ rowstart,
                            const unsigned short* __restrict__ rank,
                            unsigned int* __restrict__ ecv,
                            const float* __restrict__ x, unsigned short* __restrict__ xb) {
    int t = blockIdx.x * blockDim.x + threadIdx.x;
    if (t < NE) {
        int r = row[t], c = col[t];
        int pos = rowstart[r] + (int)rank[t];
        ecv[pos] = (unsigned int)(unsigned short)c | ((unsigned int)f2bf(ea[t]) << 16);
    } else {
        int j = t - NE;
        if (j < (NN * DF) / 8) {
            float dv = dinv[j >> 3];
            const float4* xf = (const float4*)x;
            float4 f0 = xf[2 * j];
            float4 f1 = xf[2 * j + 1];
            uint4 o;
            o.x = (unsigned int)f2bf(dv * f0.x) | ((unsigned int)f2bf(dv * f0.y) << 16);
            o.y = (unsigned int)f2bf(dv * f0.z) | ((unsigned int)f2bf(dv * f0.w) << 16);
            o.z = (unsigned int)f2bf(dv * f1.x) | ((unsigned int)f2bf(dv * f1.y) << 16);
            o.w = (unsigned int)f2bf(dv * f1.z) | ((unsigned int)f2bf(dv * f1.w) << 16);
            ((uint4*)xb)[j] = o;
        }
    }
}

__global__ __launch_bounds__(256, 8) void k_spmm(
    const int* __restrict__ rowstart, const float* __restrict__ dinv,
    const unsigned int* __restrict__ ecv, const unsigned short* __restrict__ xin,
    unsigned short* __restrict__ bout) {
    int wv = (blockIdx.x * blockDim.x + threadIdx.x) >> 6;
    if (wv >= NN / 2) return;
    spmm_layer(rowstart, dinv, ecv, xin, bout, wv, 1 << 30, threadIdx.x & 63);
}

__global__ __launch_bounds__(256, 8) void k_spmm_comb(
    const int* __restrict__ rowstart, const float* __restrict__ dinv,
    const float* __restrict__ sqd,
    const unsigned int* __restrict__ ecv, const unsigned short* __restrict__ xin,
    const float* __restrict__ x, const unsigned short* __restrict__ xb1,
    const float* __restrict__ gamma, float* __restrict__ out) {
    int wv = (blockIdx.x * blockDim.x + threadIdx.x) >> 6;
    if (wv >= NN / 2) return;
    int lane = threadIdx.x & 63;
    int h = lane >> 5, fp = lane & 31;
    int r = 2 * wv + h;
    int s = rowstart[r];
    int so = __shfl_xor(s, 32, 64);
    int m = h ? (s - so) : (so - s);
    float a0 = 0.f, a1 = 0.f;
    spmm_pair(ecv, s, m, xin, fp, a0, a1);
    float dv = dinv[r];
    a0 *= dv; a1 *= dv;
    float sq = sqd[r];
    int base = r * DF + 2 * fp;
    float2 v0 = *(const float2*)(x + base);
    unsigned int u1 = *(const unsigned int*)(xb1 + base);
    unsigned int u2 = *(const unsigned int*)(xin + base);
    float v1l = __uint_as_float(u1 << 16) * sq;
    float v1h = __uint_as_float(u1 & 0xFFFF0000u) * sq;
    float v2l = __uint_as_float(u2 << 16) * sq;
    float v2h = __uint_as_float(u2 & 0xFFFF0000u) * sq;
    float gm[OUT_K * OUT_K];
    #pragma unroll
    for (int t = 0; t < OUT_K * OUT_K; ++t) gm[t] = gamma[t];
    #pragma unroll
    for (int k = 0; k < OUT_K; ++k) {
        float2 o;
        o.x = gm[k * OUT_K + 0] * v0.x + gm[k * OUT_K + 1] * v1l +
              gm[k * OUT_K + 2] * v2l + gm[k * OUT_K + 3] * a0;
        o.y = gm[k * OUT_K + 0] * v0.y + gm[k * OUT_K + 1] * v1h +
              gm[k * OUT_K + 2] * v2h + gm[k * OUT_K + 3] * a1;
        *(float2*)(out + (r * OUT_K + k) * DF + 2 * fp) = o;
    }
}

// ---------------- launch ----------------

extern "C" void kernel_launch(void* const* d_in, const int* in_sizes, int n_in,
                              void* d_out, int out_size, void* d_ws, size_t ws_size,
                              hipStream_t stream) {
    const float* x      = (const float*)d_in[0];
    const int*   ei     = (const int*)d_in[1];
    const float* ea     = (const float*)d_in[2];
    const float* alphas = (const float*)d_in[3];
    const float* w      = (const float*)d_in[4];
    const float* a_arr  = (const float*)d_in[5];
    const float* b_arr  = (const float*)d_in[6];
    float* out = (float*)d_out;
    const int* row = ei;
    const int* col = ei + NE;

    char* ws = (char*)d_ws;
    size_t off = 0;
    auto alloc = [&](size_t bytes) {
        void* p = ws + off;
        off = (off + bytes + 255) & ~(size_t)255;
        return p;
    };
    // deg/counter then ecv are contiguous so ONE memset zeroes all
    // (ecv pad slots must be 0: col=0, bf16 weight=+0).
    int* deg      = (int*)alloc((size_t)(NN + 1) * sizeof(int));
    int* counter  = deg + NN;
    unsigned int* ecv = (unsigned int*)alloc((size_t)SLAB_CAP * sizeof(unsigned int));
    size_t zero_end = off;
    int* rowstart = (int*)alloc((size_t)NN * sizeof(int));
    float* dinv   = (float*)alloc((size_t)NN * sizeof(float));
    float* sqd    = (float*)alloc((size_t)NN * sizeof(float));
    unsigned short* rank = (unsigned short*)alloc((size_t)NE * sizeof(unsigned short));
    unsigned short* xb0 = (unsigned short*)alloc((size_t)NN * DF * sizeof(unsigned short));
    unsigned short* xb1 = (unsigned short*)alloc((size_t)NN * DF * sizeof(unsigned short));
    unsigned short* xb2 = (unsigned short*)alloc((size_t)NN * DF * sizeof(unsigned short));
    float* gamma = (float*)alloc((size_t)OUT_K * OUT_K * sizeof(float));

    (void)hipMemsetAsync(deg, 0, zero_end, stream);

    void* args[] = {&row, &col, &ea, &x, &alphas, &w, &a_arr, &b_arr,
                    &deg, &counter, &ecv, &rowstart, &dinv, &sqd, &rank,
                    &xb0, &xb1, &xb2, &gamma, &out};
    hipError_t err = hipLaunchCooperativeKernel((void*)k_mega, dim3(GRID_CO), dim3(256),
                                                args, 0, stream);
    if (err != hipSuccess) {
        // fallback: proven 6-kernel pipeline
        k_deg<<<(NE + 255) / 256, 256, 0, stream>>>(row, deg, rank);
        k_alloc<<<(NN + 1023) / 1024, 1024, 0, stream>>>(deg, counter, rowstart, dinv,
                                                         sqd, alphas, w, a_arr, b_arr,
                                                         gamma);
        k_fill_cast<<<(NE + (NN * DF) / 8 + 255) / 256, 256, 0, stream>>>(
            row, col, ea, dinv, rowstart, rank, ecv, x, xb0);
        int blocks = (NN / 2 + 3) / 4;
        k_spmm<<<blocks, 256, 0, stream>>>(rowstart, dinv, ecv, xb0, xb1);
        k_spmm<<<blocks, 256, 0, stream>>>(rowstart, dinv, ecv, xb1, xb2);
        k_spmm_comb<<<blocks, 256, 0, stream>>>(rowstart, dinv, sqd, ecv, xb2, x, xb1,
                                                gamma, out);
    }
}

// Round 9
// 208.889 us; speedup vs baseline: 6.1218x; 6.1218x over previous
//
#include <hip/hip_runtime.h>
#include <hip/hip_fp16.h>

#define NN 50000      // nodes (fits in 16 bits: col packed as ushort)
#define NE 800000     // edges
#define DF 64         // features
#define MM 11         // (a,b) tuples
#define OUT_K 4       // DEPTH+1 output planes
#define PAD 16        // row slabs padded to multiple of PAD (16: best-measured SpMM batch)
// pair-max padding: each row pair padded to 2*max -> bounded by 2*sum
#define SLAB_CAP (2 * (NE + (PAD - 1) * NN) + 128)

typedef unsigned int uivec4 __attribute__((ext_vector_type(4)));

__device__ __forceinline__ float bf2f(unsigned short u) {
    union { unsigned int i; float f; } v; v.i = ((unsigned int)u) << 16; return v.f;
}
__device__ __forceinline__ unsigned short f2bf(float f) {
    union { float f; unsigned int i; } v; v.f = f;
    unsigned int u = v.i + 0x7FFFu + ((v.i >> 16) & 1u);
    return (unsigned short)(u >> 16);
}

// ---------------- CSR build ----------------

// deg AND per-edge rank within its row (the atomic's old value — free sort key)
__global__ void k_deg(const int* __restrict__ row, int* __restrict__ deg,
                      unsigned short* __restrict__ rank) {
    int e = blockIdx.x * blockDim.x + threadIdx.x;
    if (e < NE) {
        int r = row[e];
        rank[e] = (unsigned short)atomicAdd(&deg[r], 1);
    }
}

// slab alloc: 1024-thread blocks, two-level (wave shfl + LDS) scan,
// ONE atomic per block. Row pairs (2i,2i+1) padded to a COMMON length
// m = max(pad(deg_2i), pad(deg_2i+1)); m recoverable as rowstart diff.
// Emits dinv = deg^-1/2 and sqd = deg^+1/2 (deg clamped >=1).
// gamma parallelized over m on wave 0 of block 0.
__global__ __launch_bounds__(1024) void k_alloc(
        const int* __restrict__ deg, int* __restrict__ counter,
        int* __restrict__ rowstart, float* __restrict__ dinv,
        float* __restrict__ sqd,
        const float* __restrict__ alphas, const float* __restrict__ w,
        const float* __restrict__ a_arr, const float* __restrict__ b_arr,
        float* __restrict__ gamma) {
    __shared__ int wtot[16];
    __shared__ int blockbase;
    int i = blockIdx.x * 1024 + threadIdx.x;
    int wave = threadIdx.x >> 6;
    int lane = threadIdx.x & 63;

    int d = (i < NN) ? deg[i] : 0;
    int dp = (d + PAD - 1) & ~(PAD - 1);
    int dpo = __shfl_xor(dp, 1, 64);      // pair partner's padded length
    int mp = max(dp, dpo);                // common pair length
    int v = mp;
    #pragma unroll
    for (int off = 1; off < 64; off <<= 1) {
        int t = __shfl_up(v, off, 64);
        if (lane >= off) v += t;
    }
    if (lane == 63) wtot[wave] = v;
    __syncthreads();
    if (wave == 0) {
        int t = (lane < 16) ? wtot[lane] : 0;
        #pragma unroll
        for (int off = 1; off < 16; off <<= 1) {
            int u = __shfl_up(t, off, 64);
            if (lane >= off) t += u;
        }
        if (lane == 15) blockbase = atomicAdd(counter, t);  // block total
        if (lane < 16) wtot[lane] = t;                      // inclusive scan
    }
    __syncthreads();
    int base = blockbase + (wave ? wtot[wave - 1] : 0);
    if (i < NN) {
        rowstart[i] = base + v - mp;      // even row: pair base; odd: base+m
        float dc = (float)(d == 0 ? 1 : d);
        float s = sqrtf(dc);
        sqd[i] = s;
        dinv[i] = 1.0f / s;
    }

    // gamma[k][j] = sum_m w_m c_{k,m,j}: one m per lane, shuffle-reduce.
    if (blockIdx.x == 0 && wave == 0) {
        float g[OUT_K][OUT_K];
        #pragma unroll
        for (int k = 0; k < OUT_K; ++k)
            #pragma unroll
            for (int j = 0; j < OUT_K; ++j) g[k][j] = 0.f;
        if (lane < MM) {
            int m = lane;
            float a = a_arr[m], b = b_arr[m], wm = w[m];
            float c[OUT_K][OUT_K];
            #pragma unroll
            for (int k = 0; k < OUT_K; ++k)
                #pragma unroll
                for (int j = 0; j < OUT_K; ++j) c[k][j] = 0.f;
            c[0][0] = 1.f;
            float al0 = alphas[m];
            c[1][0] = al0 * 0.5f * (a - b);        // l=-1, r=1
            c[1][1] = al0 * 0.5f * (a + b + 2.f);
            #pragma unroll
            for (int L = 2; L <= 3; ++L) {
                float Lf = (float)L;
                float alL = alphas[(L - 1) * MM + m];
                float alm = alphas[(L - 2) * MM + m];
                float ab = a + b;
                float t2L = 2.f * Lf + ab;
                float coef_l = 2.f * Lf * (Lf + ab) * (t2L - 2.f);
                float inv = 1.f / coef_l;
                float t1 = alL * ((t2L - 1.f) * t2L * (t2L - 2.f)) * inv;
                float t2 = alL * ((t2L - 1.f) * (a * a - b * b)) * inv;
                float t3 = alL * alm * (2.f * (Lf - 1.f + a) * (Lf - 1.f + b) * t2L) * inv;
                #pragma unroll
                for (int j = 0; j < OUT_K; ++j) {
                    float ps = (j > 0) ? c[L - 1][j - 1] : 0.f;
                    c[L][j] = t1 * ps - t2 * c[L - 1][j] - t3 * c[L - 2][j];
                }
            }
            #pragma unroll
            for (int k = 0; k < OUT_K; ++k)
                #pragma unroll
                for (int j = 0; j < OUT_K; ++j) g[k][j] = wm * c[k][j];
        }
        #pragma unroll
        for (int k = 0; k < OUT_K; ++k)
            #pragma unroll
            for (int j = 0; j < OUT_K; ++j) {
                float s = g[k][j];
                #pragma unroll
                for (int off = 32; off >= 1; off >>= 1) s += __shfl_down(s, off, 64);
                if (lane == 0) gamma[k * OUT_K + j] = s;
            }
    }
}

// fill (atomic-free: pos = rowstart + precomputed rank) + bf16 cast of the
// dinv-prescaled gather table xs0 = dinv[node]*x.
// Record: low16 = col, high16 = bf16(ea) ONLY — no per-edge dinv[col] gather;
// dinv[col] lives in the table, dinv[row] applied at SpMM output.
__global__ void k_fill_cast(const int* __restrict__ row, const int* __restrict__ col,
                            const float* __restrict__ ea, const float* __restrict__ dinv,
                            const int* __restrict__ rowstart,
                            const unsigned short* __restrict__ rank,
                            unsigned int* __restrict__ ecv,
                            const float* __restrict__ x, unsigned short* __restrict__ xb) {
    int t = blockIdx.x * blockDim.x + threadIdx.x;
    if (t < NE) {
        int r = row[t], c = col[t];
        int pos = rowstart[r] + (int)rank[t];
        ecv[pos] = (unsigned int)(unsigned short)c | ((unsigned int)f2bf(ea[t]) << 16);
    } else {
        int j = t - NE;
        if (j < (NN * DF) / 8) {
            float dv = dinv[j >> 3];               // 8 threads share a node
            const float4* xf = (const float4*)x;
            float4 f0 = xf[2 * j];
            float4 f1 = xf[2 * j + 1];
            uint4 o;
            o.x = (unsigned int)f2bf(dv * f0.x) | ((unsigned int)f2bf(dv * f0.y) << 16);
            o.y = (unsigned int)f2bf(dv * f0.z) | ((unsigned int)f2bf(dv * f0.w) << 16);
            o.z = (unsigned int)f2bf(dv * f1.x) | ((unsigned int)f2bf(dv * f1.y) << 16);
            o.w = (unsigned int)f2bf(dv * f1.z) | ((unsigned int)f2bf(dv * f1.w) << 16);
            ((uint4*)xb)[j] = o;
        }
    }
}

// ------ SpMM: wave = row PAIR; lanes 0-31 row 2w, lanes 32-63 row 2w+1 ------
// Each lane covers 2 features (one uint gather = 2 bf16). Table is
// dinv-prescaled, so raw = sum(ea * xs[col]); y = dinv[row]*raw.
__device__ __forceinline__ void spmm_pair(const unsigned int* __restrict__ ecv,
                                          int s, int m,
                                          const unsigned short* __restrict__ xin,
                                          int fp, float& a0, float& a1) {
    for (int i = 0; i < m; i += PAD) {
        const uivec4* p = (const uivec4*)(ecv + s + i);
        uivec4 q0 = __builtin_nontemporal_load(p);
        uivec4 q1 = __builtin_nontemporal_load(p + 1);
        uivec4 q2 = __builtin_nontemporal_load(p + 2);
        uivec4 q3 = __builtin_nontemporal_load(p + 3);
        unsigned int rec[PAD] = {q0.x, q0.y, q0.z, q0.w, q1.x, q1.y, q1.z, q1.w,
                                 q2.x, q2.y, q2.z, q2.w, q3.x, q3.y, q3.z, q3.w};
        unsigned int g[PAD];
        #pragma unroll
        for (int j = 0; j < PAD; ++j)
            g[j] = *(const unsigned int*)(xin + (rec[j] & 0xFFFFu) * DF + 2 * fp);
        #pragma unroll
        for (int j = 0; j < PAD; ++j) {
            float wf = __uint_as_float(rec[j] & 0xFFFF0000u);  // bf16 weight (ea)
            a0 = fmaf(wf, __uint_as_float(g[j] << 16), a0);
            a1 = fmaf(wf, __uint_as_float(g[j] & 0xFFFF0000u), a1);
        }
    }
}

// Stores the NEXT layer's prescaled table: xs_next = dinv[r]*y = dinv[r]^2*raw.
__global__ __launch_bounds__(256, 8) void k_spmm(
    const int* __restrict__ rowstart, const float* __restrict__ dinv,
    const unsigned int* __restrict__ ecv, const unsigned short* __restrict__ xin,
    unsigned short* __restrict__ bout) {
    int wv = (blockIdx.x * blockDim.x + threadIdx.x) >> 6;  // pair index
    if (wv >= NN / 2) return;
    int lane = threadIdx.x & 63;
    int h = lane >> 5, fp = lane & 31;
    int r = 2 * wv + h;
    int s = rowstart[r];
    int so = __shfl_xor(s, 32, 64);
    int m = h ? (s - so) : (so - s);     // common pair length
    float a0 = 0.f, a1 = 0.f;
    spmm_pair(ecv, s, m, xin, fp, a0, a1);
    float dv = dinv[r];
    float dv2 = dv * dv;
    a0 *= dv2; a1 *= dv2;
    unsigned int o = (unsigned int)f2bf(a0) | ((unsigned int)f2bf(a1) << 16);
    *(unsigned int*)(bout + r * DF + 2 * fp) = o;
}

// third SpMM with the output combine fused (y3 never hits memory);
// tables are prescaled by dinv[r], so y_k = table_k[r] * sqd[r].
__global__ __launch_bounds__(256, 8) void k_spmm_comb(
    const int* __restrict__ rowstart, const float* __restrict__ dinv,
    const float* __restrict__ sqd,
    const unsigned int* __restrict__ ecv, const unsigned short* __restrict__ xin,
    const float* __restrict__ x, const unsigned short* __restrict__ xb1,
    const float* __restrict__ gamma, float* __restrict__ out) {
    int wv = (blockIdx.x * blockDim.x + threadIdx.x) >> 6;
    if (wv >= NN / 2) return;
    int lane = threadIdx.x & 63;
    int h = lane >> 5, fp = lane & 31;
    int r = 2 * wv + h;
    int s = rowstart[r];
    int so = __shfl_xor(s, 32, 64);
    int m = h ? (s - so) : (so - s);
    float a0 = 0.f, a1 = 0.f;
    spmm_pair(ecv, s, m, xin, fp, a0, a1);
    float dv = dinv[r];
    a0 *= dv; a1 *= dv;                   // v3 pair (y3 = dinv*raw)
    float sq = sqd[r];
    int base = r * DF + 2 * fp;
    float2 v0 = *(const float2*)(x + base);
    unsigned int u1 = *(const unsigned int*)(xb1 + base);
    unsigned int u2 = *(const unsigned int*)(xin + base);   // xin == xs2 table
    float v1l = __uint_as_float(u1 << 16) * sq;
    float v1h = __uint_as_float(u1 & 0xFFFF0000u) * sq;
    float v2l = __uint_as_float(u2 << 16) * sq;
    float v2h = __uint_as_float(u2 & 0xFFFF0000u) * sq;
    float gm[OUT_K * OUT_K];
    #pragma unroll
    for (int t = 0; t < OUT_K * OUT_K; ++t) gm[t] = gamma[t];
    #pragma unroll
    for (int k = 0; k < OUT_K; ++k) {
        float2 o;
        o.x = gm[k * OUT_K + 0] * v0.x + gm[k * OUT_K + 1] * v1l +
              gm[k * OUT_K + 2] * v2l + gm[k * OUT_K + 3] * a0;
        o.y = gm[k * OUT_K + 0] * v0.y + gm[k * OUT_K + 1] * v1h +
              gm[k * OUT_K + 2] * v2h + gm[k * OUT_K + 3] * a1;
        *(float2*)(out + (r * OUT_K + k) * DF + 2 * fp) = o;
    }
}

// ---------------- launch ----------------

extern "C" void kernel_launch(void* const* d_in, const int* in_sizes, int n_in,
                              void* d_out, int out_size, void* d_ws, size_t ws_size,
                              hipStream_t stream) {
    const float* x      = (const float*)d_in[0];
    const int*   ei     = (const int*)d_in[1];
    const float* ea     = (const float*)d_in[2];
    const float* alphas = (const float*)d_in[3];
    const float* w      = (const float*)d_in[4];
    const float* a_arr  = (const float*)d_in[5];
    const float* b_arr  = (const float*)d_in[6];
    float* out = (float*)d_out;
    const int* row = ei;
    const int* col = ei + NE;

    char* ws = (char*)d_ws;
    size_t off = 0;
    auto alloc = [&](size_t bytes) {
        void* p = ws + off;
        off = (off + bytes + 255) & ~(size_t)255;
        return p;
    };
    // deg/counter then ecv are contiguous so ONE memset zeroes all
    // (ecv pad slots must be 0: col=0, bf16 weight=+0).
    int* deg      = (int*)alloc((size_t)(NN + 1) * sizeof(int));
    int* counter  = deg + NN;
    unsigned int* ecv = (unsigned int*)alloc((size_t)SLAB_CAP * sizeof(unsigned int));
    size_t zero_end = off;
    int* rowstart = (int*)alloc((size_t)NN * sizeof(int));
    float* dinv   = (float*)alloc((size_t)NN * sizeof(float));
    float* sqd    = (float*)alloc((size_t)NN * sizeof(float));
    unsigned short* rank = (unsigned short*)alloc((size_t)NE * sizeof(unsigned short));
    unsigned short* xb0 = (unsigned short*)alloc((size_t)NN * DF * sizeof(unsigned short));
    unsigned short* xb1 = (unsigned short*)alloc((size_t)NN * DF * sizeof(unsigned short));
    unsigned short* xb2 = (unsigned short*)alloc((size_t)NN * DF * sizeof(unsigned short));
    float* gamma = (float*)alloc((size_t)OUT_K * OUT_K * sizeof(float));

    (void)hipMemsetAsync(deg, 0, zero_end, stream);

    k_deg<<<(NE + 255) / 256, 256, 0, stream>>>(row, deg, rank);
    k_alloc<<<(NN + 1023) / 1024, 1024, 0, stream>>>(deg, counter, rowstart, dinv, sqd,
                                                     alphas, w, a_arr, b_arr, gamma);
    k_fill_cast<<<(NE + (NN * DF) / 8 + 255) / 256, 256, 0, stream>>>(
        row, col, ea, dinv, rowstart, rank, ecv, x, xb0);

    int blocks = (NN / 2 + 3) / 4;  // one wave per row PAIR, 4 pairs/block
    k_spmm<<<blocks, 256, 0, stream>>>(rowstart, dinv, ecv, xb0, xb1);
    k_spmm<<<blocks, 256, 0, stream>>>(rowstart, dinv, ecv, xb1, xb2);
    k_spmm_comb<<<blocks, 256, 0, stream>>>(rowstart, dinv, sqd, ecv, xb2, x, xb1,
                                            gamma, out);
}